// Round 6
// baseline (190.650 us; speedup 1.0000x reference)
//
#include <hip/hip_runtime.h>
#include <cmath>

#define NB 8
#define CC 256
#define NPIX 4096
#define QB 64
#define KVB 64
#define LOG2E 1.4426950408889634f

typedef __attribute__((ext_vector_type(4))) float f32x4;
typedef __attribute__((ext_vector_type(8))) short s16x8;
typedef __attribute__((ext_vector_type(4))) unsigned short u16x4;
typedef __attribute__((ext_vector_type(4))) unsigned int u32x4;
typedef __attribute__((ext_vector_type(2))) unsigned int u32x2;

__device__ __forceinline__ unsigned short f2bf(float f) {
    union { float f; unsigned int u; } v; v.f = f;
    return (unsigned short)((v.u + 0x7FFFu + ((v.u >> 16) & 1u)) >> 16);
}

__device__ __forceinline__ unsigned int cvt_pk_bf16(float lo, float hi) {
    unsigned int r;
    asm("v_cvt_pk_bf16_f32 %0, %1, %2" : "=v"(r) : "v"(lo), "v"(hi));
    return r;  // low16 = bf16(lo), high16 = bf16(hi), RNE
}

__device__ __forceinline__ float u2f(unsigned int u) {
    union { unsigned int u; float f; } v; v.u = u; return v.f;
}

// ---------------------------------------------------------------------------
// proj_gemm: [Q(32);K(32);V(256)] = W · x  via MFMA, 2-term x hi/lo split.
// (unchanged from R4 — passed, ~14 µs)
// ---------------------------------------------------------------------------
__global__ __launch_bounds__(320) void proj_gemm_kernel(
    const float* __restrict__ x,
    const float* __restrict__ w1, const float* __restrict__ b1,
    const float* __restrict__ w2, const float* __restrict__ b2,
    const float* __restrict__ w3, const float* __restrict__ b3,
    unsigned short* __restrict__ Qm, unsigned short* __restrict__ Km,
    unsigned short* __restrict__ Vm)
{
    const int b  = blockIdx.x >> 6;
    const int n0 = (blockIdx.x & 63) * 64;
    const int wave = threadIdx.x >> 6;
    const int lane = threadIdx.x & 63;
    const int cl = lane & 15, g = lane >> 4;

    const float* arow[4];
#pragma unroll
    for (int ct = 0; ct < 4; ++ct) {
        const int row = wave * 64 + ct * 16 + cl;  // 0..319
        if (row < 32)       arow[ct] = w1 + (size_t)row * 256;
        else if (row < 64)  arow[ct] = w2 + (size_t)(row - 32) * 256;
        else                arow[ct] = w3 + (size_t)(row - 64) * 256;
    }

    const float* xb = x + (size_t)b * CC * NPIX + n0 + cl;

    f32x4 acc[4][4];
#pragma unroll
    for (int ct = 0; ct < 4; ++ct)
#pragma unroll
        for (int nt = 0; nt < 4; ++nt) acc[ct][nt] = (f32x4){0.f, 0.f, 0.f, 0.f};

    for (int ks = 0; ks < 8; ++ks) {
        const int c0 = ks * 32;
        s16x8 ah[4];
#pragma unroll
        for (int ct = 0; ct < 4; ++ct) {
            const float* ap = arow[ct] + c0 + g * 8;
            f32x4 a0 = *(const f32x4*)ap;
            f32x4 a1 = *(const f32x4*)(ap + 4);
            u32x4 u;
            u[0] = cvt_pk_bf16(a0[0], a0[1]); u[1] = cvt_pk_bf16(a0[2], a0[3]);
            u[2] = cvt_pk_bf16(a1[0], a1[1]); u[3] = cvt_pk_bf16(a1[2], a1[3]);
            ah[ct] = __builtin_bit_cast(s16x8, u);
        }
#pragma unroll
        for (int nt = 0; nt < 4; ++nt) {
            const float* xp = xb + (size_t)(c0 + g * 8) * NPIX + nt * 16;
            float xe[8];
#pragma unroll
            for (int e = 0; e < 8; ++e) xe[e] = xp[(size_t)e * NPIX];
            u32x4 uh, ul;
#pragma unroll
            for (int p = 0; p < 4; ++p) {
                const unsigned int hp = cvt_pk_bf16(xe[2 * p], xe[2 * p + 1]);
                const float h0 = u2f(hp << 16);
                const float h1 = u2f(hp & 0xffff0000u);
                uh[p] = hp;
                ul[p] = cvt_pk_bf16(xe[2 * p] - h0, xe[2 * p + 1] - h1);
            }
            const s16x8 bh = __builtin_bit_cast(s16x8, uh);
            const s16x8 bl = __builtin_bit_cast(s16x8, ul);
#pragma unroll
            for (int ct = 0; ct < 4; ++ct)
                acc[ct][nt] = __builtin_amdgcn_mfma_f32_16x16x32_bf16(ah[ct], bh, acc[ct][nt], 0, 0, 0);
#pragma unroll
            for (int ct = 0; ct < 4; ++ct)
                acc[ct][nt] = __builtin_amdgcn_mfma_f32_16x16x32_bf16(ah[ct], bl, acc[ct][nt], 0, 0, 0);
        }
    }

    if (wave == 0) {
#pragma unroll
        for (int ct = 0; ct < 4; ++ct) {
#pragma unroll
            for (int nt = 0; nt < 4; ++nt) {
                const int n = n0 + nt * 16 + cl;
                const int co = ct * 16 + g * 4;
                f32x4 v = acc[ct][nt];
                if (ct < 2) {  // Q, pre-scaled by log2e
                    const float q0 = (v[0] + b1[co + 0]) * LOG2E;
                    const float q1 = (v[1] + b1[co + 1]) * LOG2E;
                    const float q2 = (v[2] + b1[co + 2]) * LOG2E;
                    const float q3 = (v[3] + b1[co + 3]) * LOG2E;
                    u32x2 dd = {cvt_pk_bf16(q0, q1), cvt_pk_bf16(q2, q3)};
                    *(u32x2*)(Qm + ((size_t)b * NPIX + n) * 32 + co) = dd;
                } else {
                    const int ko = co - 32;
                    const float k0 = v[0] + b2[ko + 0];
                    const float k1 = v[1] + b2[ko + 1];
                    const float k2 = v[2] + b2[ko + 2];
                    const float k3 = v[3] + b2[ko + 3];
                    u32x2 dd = {cvt_pk_bf16(k0, k1), cvt_pk_bf16(k2, k3)};
                    *(u32x2*)(Km + ((size_t)b * NPIX + n) * 32 + ko) = dd;
                }
            }
        }
    } else {
        const int cvb = (wave - 1) * 64;
#pragma unroll
        for (int ct = 0; ct < 4; ++ct) {
#pragma unroll
            for (int nt = 0; nt < 4; ++nt) {
                const int n = n0 + nt * 16 + cl;
                const int cv = cvb + ct * 16 + g * 4;
#pragma unroll
                for (int r = 0; r < 4; ++r)
                    Vm[((size_t)b * CC + cv + r) * NPIX + n] = f2bf(acc[ct][nt][r] + b3[cv + r]);
            }
        }
    }
}

// ---------------------------------------------------------------------------
// attn v5: R4's PROVEN two-barrier sync skeleton (single-buffered Ps/alpha),
// but K and V read directly from global (L2-resident via per-XCD batch
// swizzle) — no V/K LDS, no V-commit. K prefetched one tile ahead
// (unconditional, wrap-indexed — no conditionally-initialized regs); V A-frags
// issued at iter top, used after barrier2 (~400cyc later). Lean VGPR (~190).
// grid: 512 blocks (8 batches x 64 q-blocks), 256 threads = 4 waves
// ---------------------------------------------------------------------------
__global__ __launch_bounds__(256, 2) void attn_kernel(
    const unsigned short* __restrict__ Qm, const unsigned short* __restrict__ Km,
    const unsigned short* __restrict__ Vm, const float* __restrict__ gamma,
    float* __restrict__ out)
{
    __shared__ unsigned short Ps[QB * KVB];  // [q][m] 8KB, swizzled, shared
    __shared__ float alpha_lds[QB];          // per-q rescale factor, this tile
    __shared__ float l_lds[QB];              // final denominators

    // XCD swizzle: each XCD gets one batch's 64 q-blocks (K+V fit its 4MB L2)
    const int bid = ((blockIdx.x & 7) << 6) + (blockIdx.x >> 3);
    const int b = bid >> 6;
    const int q0 = (bid & 63) * QB;

    const int t = threadIdx.x;
    const int wave = t >> 6;
    const int lane = t & 63;
    const int cl = lane & 15;
    const int g = lane >> 4;
    const int c0w = wave * 64;            // this wave's channel slice
    const int qrow_own = wave * 16 + cl;  // this wave's softmax q-row

    // Q B-frag for the private q-slice: B[k=d][col=q]
    const s16x8 qf = *(const s16x8*)(Qm + (((size_t)b * NPIX) + q0 + qrow_own) * 32 + g * 8);

    f32x4 acc[4][4];  // [qt][ct]: q = qt*16+cl, c = c0w + ct*16 + g*4 + r
#pragma unroll
    for (int qt = 0; qt < 4; ++qt)
#pragma unroll
        for (int ct = 0; ct < 4; ++ct)
            acc[qt][ct] = (f32x4){0.f, 0.f, 0.f, 0.f};

    float mrun = -__builtin_inff();
    float lrun = 0.f;  // per-lane partial; g-reduced once in epilogue

    // per-lane base pointers
    const unsigned short* kbase = Km + (size_t)b * NPIX * 32 + (size_t)cl * 32 + g * 8;
    const unsigned short* vbase = Vm + ((size_t)b * CC + c0w + cl) * NPIX + g * 8;

    // prologue: K frags for tile 0: A[row=m][k=d]
    s16x8 kf[4];
#pragma unroll
    for (int mt = 0; mt < 4; ++mt)
        kf[mt] = *(const s16x8*)(kbase + (size_t)(mt * 16) * 32);

    for (int it = 0; it < NPIX / KVB; ++it) {
        const int m0 = it * KVB;

        __syncthreads();  // barrier1: prev iter's Ps/alpha reads complete

        // V A-frags for THIS tile (global, L2): used after barrier2 (~400cyc)
        s16x8 av[2][4];
#pragma unroll
        for (int ch = 0; ch < 2; ++ch)
#pragma unroll
            for (int ct = 0; ct < 4; ++ct)
                av[ch][ct] = *(const s16x8*)(vbase + (size_t)(ct * 16) * NPIX + m0 + ch * 32);

        // QK^T for private q-slice: S^T tiles D[row=m][col=q]
        f32x4 s[4];
        __builtin_amdgcn_s_setprio(1);
#pragma unroll
        for (int mt = 0; mt < 4; ++mt) {
            f32x4 z = (f32x4){0.f, 0.f, 0.f, 0.f};
            s[mt] = __builtin_amdgcn_mfma_f32_16x16x32_bf16(kf[mt], qf, z, 0, 0, 0);
        }
        __builtin_amdgcn_s_setprio(0);

        // prefetch next tile's K frags (unconditional; wraps to tile 0 on last
        // iter — in-bounds, result unused)
        const int itn = (it + 1) & (NPIX / KVB - 1);
        s16x8 kf2[4];
#pragma unroll
        for (int mt = 0; mt < 4; ++mt)
            kf2[mt] = *(const s16x8*)(kbase + (size_t)(itn * KVB + mt * 16) * 32);

        // online softmax over m (log2 domain; Q pre-scaled by log2e)
        float ml = -__builtin_inff();
#pragma unroll
        for (int mt = 0; mt < 4; ++mt)
#pragma unroll
            for (int r = 0; r < 4; ++r) ml = fmaxf(ml, s[mt][r]);
        ml = fmaxf(ml, __shfl_xor(ml, 16, 64));
        ml = fmaxf(ml, __shfl_xor(ml, 32, 64));

        float alpha = 1.f;
        if (!__all(ml <= mrun + 8.f)) {  // defer-max (T13)
            const float mnew = fmaxf(mrun, ml);
            alpha = __builtin_amdgcn_exp2f(mrun - mnew);
            mrun = mnew;
            lrun *= alpha;
        }
        if (g == 0) alpha_lds[qrow_own] = alpha;

#pragma unroll
        for (int mt = 0; mt < 4; ++mt) {
#pragma unroll
            for (int r = 0; r < 4; ++r) {
                s[mt][r] = __builtin_amdgcn_exp2f(s[mt][r] - mrun);
                lrun += s[mt][r];  // per-lane partial (uniform alpha across g)
            }
        }

        // pack P slice -> Ps [q][m], swizzled (8B writes via cvt_pk)
#pragma unroll
        for (int mt = 0; mt < 4; ++mt) {
            u32x2 dd = {cvt_pk_bf16(s[mt][0], s[mt][1]),
                        cvt_pk_bf16(s[mt][2], s[mt][3])};
            *(u32x2*)(&Ps[qrow_own * 64 + ((mt * 16 + g * 4) ^ ((qrow_own & 7) << 3))]) = dd;
        }

        __syncthreads();  // barrier2: Ps + alpha visible

        // rescale acc by per-q alpha (rare thanks to defer-max)
        float aq[4];
#pragma unroll
        for (int qt = 0; qt < 4; ++qt) aq[qt] = alpha_lds[qt * 16 + cl];
        if (__any(aq[0] != 1.f || aq[1] != 1.f || aq[2] != 1.f || aq[3] != 1.f)) {
#pragma unroll
            for (int qt = 0; qt < 4; ++qt)
#pragma unroll
                for (int ct = 0; ct < 4; ++ct) acc[qt][ct] *= aq[qt];
        }

        // PV: acc[qt][ct] += mfma(A=V[c][m] (regs), B=P^T[m][q] (LDS))
#pragma unroll
        for (int ch = 0; ch < 2; ++ch) {
            s16x8 pb[4];
#pragma unroll
            for (int qt = 0; qt < 4; ++qt) {
                const int qr = qt * 16 + cl;
                pb[qt] = *(const s16x8*)(&Ps[qr * 64 + ((ch * 32 + g * 8) ^ ((qr & 7) << 3))]);
            }
            __builtin_amdgcn_s_setprio(1);
#pragma unroll
            for (int ct = 0; ct < 4; ++ct)
#pragma unroll
                for (int qt = 0; qt < 4; ++qt)
                    acc[qt][ct] = __builtin_amdgcn_mfma_f32_16x16x32_bf16(av[ch][ct], pb[qt], acc[qt][ct], 0, 0, 0);
            __builtin_amdgcn_s_setprio(0);
        }

        // rotate prefetched K
#pragma unroll
        for (int mt = 0; mt < 4; ++mt) kf[mt] = kf2[mt];
    }

    // epilogue: reduce lrun over g-groups, share denominators across waves
    lrun += __shfl_xor(lrun, 16, 64);
    lrun += __shfl_xor(lrun, 32, 64);
    __syncthreads();
    if (g == 0) l_lds[qrow_own] = lrun;
    __syncthreads();

    // coalesced [b][c][n] stores; second output = gamma*val
    const float gm = gamma[0];
    float* out2 = out + (size_t)NB * CC * NPIX;
#pragma unroll
    for (int qt = 0; qt < 4; ++qt) {
        const float inv = 1.f / l_lds[qt * 16 + cl];
        const int n = q0 + qt * 16 + cl;
#pragma unroll
        for (int ct = 0; ct < 4; ++ct) {
#pragma unroll
            for (int r = 0; r < 4; ++r) {
                const int chn = c0w + ct * 16 + g * 4 + r;
                const float val = acc[qt][ct][r] * inv;
                const size_t idx = ((size_t)b * CC + chn) * NPIX + n;
                out[idx] = val;
                out2[idx] = gm * val;
            }
        }
    }
}

// ---------------------------------------------------------------------------
extern "C" void kernel_launch(void* const* d_in, const int* in_sizes, int n_in,
                              void* d_out, int out_size, void* d_ws, size_t ws_size,
                              hipStream_t stream) {
    (void)in_sizes; (void)n_in; (void)out_size; (void)ws_size;
    const float* x     = (const float*)d_in[0];
    const float* w1    = (const float*)d_in[1];
    const float* b1    = (const float*)d_in[2];
    const float* w2    = (const float*)d_in[3];
    const float* b2    = (const float*)d_in[4];
    const float* w3    = (const float*)d_in[5];
    const float* b3    = (const float*)d_in[6];
    const float* gamma = (const float*)d_in[7];
    float* out = (float*)d_out;

    unsigned short* Qm = (unsigned short*)d_ws;                       // 2 MB
    unsigned short* Km = Qm + (size_t)NB * NPIX * 32;                 // 2 MB
    unsigned short* Vm = Km + (size_t)NB * NPIX * 32;                 // 16 MB

    proj_gemm_kernel<<<NB * 64, 320, 0, stream>>>(x, w1, b1, w2, b2, w3, b3, Qm, Km, Vm);
    attn_kernel<<<NB * 64, 256, 0, stream>>>(Qm, Km, Vm, gamma, out);
}

// Round 7
// 166.997 us; speedup vs baseline: 1.1416x; 1.1416x over previous
//
#include <hip/hip_runtime.h>
#include <cmath>

#define NB 8
#define CC 256
#define NPIX 4096
#define QB 64
#define KVB 64
#define LOG2E 1.4426950408889634f

typedef __attribute__((ext_vector_type(4))) float f32x4;
typedef __attribute__((ext_vector_type(8))) short s16x8;
typedef __attribute__((ext_vector_type(4))) unsigned short u16x4;
typedef __attribute__((ext_vector_type(4))) unsigned int u32x4;
typedef __attribute__((ext_vector_type(2))) unsigned int u32x2;

__device__ __forceinline__ unsigned short f2bf(float f) {
    union { float f; unsigned int u; } v; v.f = f;
    return (unsigned short)((v.u + 0x7FFFu + ((v.u >> 16) & 1u)) >> 16);
}

__device__ __forceinline__ unsigned int cvt_pk_bf16(float lo, float hi) {
    unsigned int r;
    asm("v_cvt_pk_bf16_f32 %0, %1, %2" : "=v"(r) : "v"(lo), "v"(hi));
    return r;  // low16 = bf16(lo), high16 = bf16(hi), RNE
}

__device__ __forceinline__ float u2f(unsigned int u) {
    union { unsigned int u; float f; } v; v.u = u; return v.f;
}

// ---------------------------------------------------------------------------
// proj_gemm: [Q(32);K(32);V(256)] = W · x  via MFMA, 2-term x hi/lo split.
// (unchanged — passed, ~14 µs)
// ---------------------------------------------------------------------------
__global__ __launch_bounds__(320) void proj_gemm_kernel(
    const float* __restrict__ x,
    const float* __restrict__ w1, const float* __restrict__ b1,
    const float* __restrict__ w2, const float* __restrict__ b2,
    const float* __restrict__ w3, const float* __restrict__ b3,
    unsigned short* __restrict__ Qm, unsigned short* __restrict__ Km,
    unsigned short* __restrict__ Vm)
{
    const int b  = blockIdx.x >> 6;
    const int n0 = (blockIdx.x & 63) * 64;
    const int wave = threadIdx.x >> 6;
    const int lane = threadIdx.x & 63;
    const int cl = lane & 15, g = lane >> 4;

    const float* arow[4];
#pragma unroll
    for (int ct = 0; ct < 4; ++ct) {
        const int row = wave * 64 + ct * 16 + cl;  // 0..319
        if (row < 32)       arow[ct] = w1 + (size_t)row * 256;
        else if (row < 64)  arow[ct] = w2 + (size_t)(row - 32) * 256;
        else                arow[ct] = w3 + (size_t)(row - 64) * 256;
    }

    const float* xb = x + (size_t)b * CC * NPIX + n0 + cl;

    f32x4 acc[4][4];
#pragma unroll
    for (int ct = 0; ct < 4; ++ct)
#pragma unroll
        for (int nt = 0; nt < 4; ++nt) acc[ct][nt] = (f32x4){0.f, 0.f, 0.f, 0.f};

    for (int ks = 0; ks < 8; ++ks) {
        const int c0 = ks * 32;
        s16x8 ah[4];
#pragma unroll
        for (int ct = 0; ct < 4; ++ct) {
            const float* ap = arow[ct] + c0 + g * 8;
            f32x4 a0 = *(const f32x4*)ap;
            f32x4 a1 = *(const f32x4*)(ap + 4);
            u32x4 u;
            u[0] = cvt_pk_bf16(a0[0], a0[1]); u[1] = cvt_pk_bf16(a0[2], a0[3]);
            u[2] = cvt_pk_bf16(a1[0], a1[1]); u[3] = cvt_pk_bf16(a1[2], a1[3]);
            ah[ct] = __builtin_bit_cast(s16x8, u);
        }
#pragma unroll
        for (int nt = 0; nt < 4; ++nt) {
            const float* xp = xb + (size_t)(c0 + g * 8) * NPIX + nt * 16;
            float xe[8];
#pragma unroll
            for (int e = 0; e < 8; ++e) xe[e] = xp[(size_t)e * NPIX];
            u32x4 uh, ul;
#pragma unroll
            for (int p = 0; p < 4; ++p) {
                const unsigned int hp = cvt_pk_bf16(xe[2 * p], xe[2 * p + 1]);
                const float h0 = u2f(hp << 16);
                const float h1 = u2f(hp & 0xffff0000u);
                uh[p] = hp;
                ul[p] = cvt_pk_bf16(xe[2 * p] - h0, xe[2 * p + 1] - h1);
            }
            const s16x8 bh = __builtin_bit_cast(s16x8, uh);
            const s16x8 bl = __builtin_bit_cast(s16x8, ul);
#pragma unroll
            for (int ct = 0; ct < 4; ++ct)
                acc[ct][nt] = __builtin_amdgcn_mfma_f32_16x16x32_bf16(ah[ct], bh, acc[ct][nt], 0, 0, 0);
#pragma unroll
            for (int ct = 0; ct < 4; ++ct)
                acc[ct][nt] = __builtin_amdgcn_mfma_f32_16x16x32_bf16(ah[ct], bl, acc[ct][nt], 0, 0, 0);
        }
    }

    if (wave == 0) {
#pragma unroll
        for (int ct = 0; ct < 4; ++ct) {
#pragma unroll
            for (int nt = 0; nt < 4; ++nt) {
                const int n = n0 + nt * 16 + cl;
                const int co = ct * 16 + g * 4;
                f32x4 v = acc[ct][nt];
                if (ct < 2) {  // Q, pre-scaled by log2e
                    const float q0 = (v[0] + b1[co + 0]) * LOG2E;
                    const float q1 = (v[1] + b1[co + 1]) * LOG2E;
                    const float q2 = (v[2] + b1[co + 2]) * LOG2E;
                    const float q3 = (v[3] + b1[co + 3]) * LOG2E;
                    u32x2 dd = {cvt_pk_bf16(q0, q1), cvt_pk_bf16(q2, q3)};
                    *(u32x2*)(Qm + ((size_t)b * NPIX + n) * 32 + co) = dd;
                } else {
                    const int ko = co - 32;
                    const float k0 = v[0] + b2[ko + 0];
                    const float k1 = v[1] + b2[ko + 1];
                    const float k2 = v[2] + b2[ko + 2];
                    const float k3 = v[3] + b2[ko + 3];
                    u32x2 dd = {cvt_pk_bf16(k0, k1), cvt_pk_bf16(k2, k3)};
                    *(u32x2*)(Km + ((size_t)b * NPIX + n) * 32 + ko) = dd;
                }
            }
        }
    } else {
        const int cvb = (wave - 1) * 64;
#pragma unroll
        for (int ct = 0; ct < 4; ++ct) {
#pragma unroll
            for (int nt = 0; nt < 4; ++nt) {
                const int n = n0 + nt * 16 + cl;
                const int cv = cvb + ct * 16 + g * 4;
#pragma unroll
                for (int r = 0; r < 4; ++r)
                    Vm[((size_t)b * CC + cv + r) * NPIX + n] = f2bf(acc[ct][nt][r] + b3[cv + r]);
            }
        }
    }
}

// ---------------------------------------------------------------------------
// attn v6: R4's proven structure (V staged in LDS coalesced, K direct from
// L2, 2 barriers/iter, single Ps) with the grid split by channel-half:
// 1024 blocks = 8b x 64q x 2 c-halves, 4 waves/block, wave owns 32 channels.
// QK+softmax computed redundantly by the 2 sibling half-blocks (cheap).
// VGPR<=128 + LDS 25KB -> 4 blocks/CU = 16 waves/CU (was 8).
// ---------------------------------------------------------------------------
__global__ __launch_bounds__(256, 4) void attn_kernel(
    const unsigned short* __restrict__ Qm, const unsigned short* __restrict__ Km,
    const unsigned short* __restrict__ Vm, const float* __restrict__ gamma,
    float* __restrict__ out)
{
    __shared__ unsigned short Vs[128 * KVB];  // [c-half rows][m] 16KB, swizzled
    __shared__ unsigned short Ps[QB * KVB];   // [q][m] 8KB, swizzled
    __shared__ float alpha_lds[QB];           // per-q rescale factor
    __shared__ float l_lds[QB];               // final denominators

    // XCD swizzle: XCD x gets batch x's 128 (q, c-half) blocks; sibling
    // c-halves adjacent in dispatch order (share K/Q L2 lines, stay in phase)
    const int bid = ((blockIdx.x & 7) << 7) + (blockIdx.x >> 3);
    const int b = bid >> 7;
    const int rem = bid & 127;
    const int q0 = (rem >> 1) * QB;
    const int chalf = rem & 1;

    const int t = threadIdx.x;
    const int wave = t >> 6;
    const int lane = t & 63;
    const int cl = lane & 15;
    const int g = lane >> 4;
    const int c0w = wave * 32;            // within this block's 128-ch half
    const int qrow_own = wave * 16 + cl;  // this wave's softmax q-row

    // Q B-frag for the private q-slice: B[k=d][col=q]
    const s16x8 qf = *(const s16x8*)(Qm + (((size_t)b * NPIX) + q0 + qrow_own) * 32 + g * 8);

    f32x4 acc[4][2];  // [qt][ct]: q = qt*16+cl, c = chalf*128 + c0w + ct*16 + g*4 + r
#pragma unroll
    for (int qt = 0; qt < 4; ++qt)
#pragma unroll
        for (int ct = 0; ct < 2; ++ct)
            acc[qt][ct] = (f32x4){0.f, 0.f, 0.f, 0.f};

    float mrun = -__builtin_inff();
    float lrun = 0.f;  // per-lane partial; g-reduced once in epilogue

    const unsigned short* Kg = Km + (size_t)b * NPIX * 32;
    const unsigned short* Vg = Vm + ((size_t)b * CC + chalf * 128) * NPIX;

    // V staging geometry: thread covers rows cr = (t>>3) + i*32 (i<4), chunk vin
    const int vin = t & 7;
    const int vr0 = t >> 3;  // 0..31; (vr0 + i*32)&7 == vr0&7
    const unsigned short* vsrc = Vg + (size_t)vr0 * NPIX + vin * 8;
    unsigned short* vdst = &Vs[vr0 * 64 + ((vin ^ (vr0 & 7)) << 3)];

    for (int m0 = 0; m0 < NPIX; m0 += KVB) {
        __syncthreads();  // barrier1: prev iter's Vs/Ps reads complete

        // K A-frags direct from global (L2-resident): A[row=m][k=d]
        s16x8 kf[4];
#pragma unroll
        for (int mt = 0; mt < 4; ++mt)
            kf[mt] = *(const s16x8*)(Kg + (size_t)(m0 + mt * 16 + cl) * 32 + g * 8);

        // stage V half-tile [128][64] (coalesced 128B rows, swizzled slots)
#pragma unroll
        for (int i = 0; i < 4; ++i)
            *(s16x8*)(vdst + i * 32 * 64) =
                *(const s16x8*)(vsrc + (size_t)i * 32 * NPIX + m0);

        // QK^T for private q-slice: S^T tiles D[row=m][col=q]
        f32x4 s[4];
        __builtin_amdgcn_s_setprio(1);
#pragma unroll
        for (int mt = 0; mt < 4; ++mt) {
            f32x4 z = (f32x4){0.f, 0.f, 0.f, 0.f};
            s[mt] = __builtin_amdgcn_mfma_f32_16x16x32_bf16(kf[mt], qf, z, 0, 0, 0);
        }
        __builtin_amdgcn_s_setprio(0);

        // online softmax over m (log2 domain; Q pre-scaled by log2e)
        float ml = -__builtin_inff();
#pragma unroll
        for (int mt = 0; mt < 4; ++mt)
#pragma unroll
            for (int r = 0; r < 4; ++r) ml = fmaxf(ml, s[mt][r]);
        ml = fmaxf(ml, __shfl_xor(ml, 16, 64));
        ml = fmaxf(ml, __shfl_xor(ml, 32, 64));

        float alpha = 1.f;
        if (!__all(ml <= mrun + 8.f)) {  // defer-max (T13)
            const float mnew = fmaxf(mrun, ml);
            alpha = __builtin_amdgcn_exp2f(mrun - mnew);
            mrun = mnew;
            lrun *= alpha;
        }
        if (g == 0) alpha_lds[qrow_own] = alpha;

#pragma unroll
        for (int mt = 0; mt < 4; ++mt) {
#pragma unroll
            for (int r = 0; r < 4; ++r) {
                s[mt][r] = __builtin_amdgcn_exp2f(s[mt][r] - mrun);
                lrun += s[mt][r];  // per-lane partial (uniform alpha across g)
            }
        }

        // pack P slice -> Ps [q][m], swizzled (8B writes via cvt_pk)
#pragma unroll
        for (int mt = 0; mt < 4; ++mt) {
            u32x2 dd = {cvt_pk_bf16(s[mt][0], s[mt][1]),
                        cvt_pk_bf16(s[mt][2], s[mt][3])};
            *(u32x2*)(&Ps[qrow_own * 64 + ((mt * 16 + g * 4) ^ ((qrow_own & 7) << 3))]) = dd;
        }

        __syncthreads();  // barrier2: Vs + Ps + alpha visible

        // rescale acc by per-q alpha (rare thanks to defer-max)
        float aq[4];
#pragma unroll
        for (int qt = 0; qt < 4; ++qt) aq[qt] = alpha_lds[qt * 16 + cl];
        if (__any(aq[0] != 1.f || aq[1] != 1.f || aq[2] != 1.f || aq[3] != 1.f)) {
#pragma unroll
            for (int qt = 0; qt < 4; ++qt)
#pragma unroll
                for (int ct = 0; ct < 2; ++ct) acc[qt][ct] *= aq[qt];
        }

        // PV: acc[qt][ct] += mfma(A=V[c][m] (LDS), B=P^T[m][q] (LDS))
#pragma unroll
        for (int ch = 0; ch < 2; ++ch) {
            s16x8 pb[4];
#pragma unroll
            for (int qt = 0; qt < 4; ++qt) {
                const int qr = qt * 16 + cl;
                pb[qt] = *(const s16x8*)(&Ps[qr * 64 + ((ch * 32 + g * 8) ^ ((qr & 7) << 3))]);
            }
            __builtin_amdgcn_s_setprio(1);
#pragma unroll
            for (int ct = 0; ct < 2; ++ct) {
                const int cr = c0w + ct * 16 + cl;  // cr&7 == cl&7
                s16x8 av = *(const s16x8*)(&Vs[cr * 64 + ((ch * 32 + g * 8) ^ ((cr & 7) << 3))]);
#pragma unroll
                for (int qt = 0; qt < 4; ++qt)
                    acc[qt][ct] = __builtin_amdgcn_mfma_f32_16x16x32_bf16(av, pb[qt], acc[qt][ct], 0, 0, 0);
            }
            __builtin_amdgcn_s_setprio(0);
        }
    }

    // epilogue: reduce lrun over g-groups, share denominators across waves
    lrun += __shfl_xor(lrun, 16, 64);
    lrun += __shfl_xor(lrun, 32, 64);
    __syncthreads();
    if (g == 0) l_lds[qrow_own] = lrun;
    __syncthreads();

    // coalesced [b][c][n] stores; second output = gamma*val
    const float gm = gamma[0];
    float* out2 = out + (size_t)NB * CC * NPIX;
#pragma unroll
    for (int qt = 0; qt < 4; ++qt) {
        const float inv = 1.f / l_lds[qt * 16 + cl];
        const int n = q0 + qt * 16 + cl;
#pragma unroll
        for (int ct = 0; ct < 2; ++ct) {
#pragma unroll
            for (int r = 0; r < 4; ++r) {
                const int chn = chalf * 128 + c0w + ct * 16 + g * 4 + r;
                const float val = acc[qt][ct][r] * inv;
                const size_t idx = ((size_t)b * CC + chn) * NPIX + n;
                out[idx] = val;
                out2[idx] = gm * val;
            }
        }
    }
}

// ---------------------------------------------------------------------------
extern "C" void kernel_launch(void* const* d_in, const int* in_sizes, int n_in,
                              void* d_out, int out_size, void* d_ws, size_t ws_size,
                              hipStream_t stream) {
    (void)in_sizes; (void)n_in; (void)out_size; (void)ws_size;
    const float* x     = (const float*)d_in[0];
    const float* w1    = (const float*)d_in[1];
    const float* b1    = (const float*)d_in[2];
    const float* w2    = (const float*)d_in[3];
    const float* b2    = (const float*)d_in[4];
    const float* w3    = (const float*)d_in[5];
    const float* b3    = (const float*)d_in[6];
    const float* gamma = (const float*)d_in[7];
    float* out = (float*)d_out;

    unsigned short* Qm = (unsigned short*)d_ws;                       // 2 MB
    unsigned short* Km = Qm + (size_t)NB * NPIX * 32;                 // 2 MB
    unsigned short* Vm = Km + (size_t)NB * NPIX * 32;                 // 16 MB

    proj_gemm_kernel<<<NB * 64, 320, 0, stream>>>(x, w1, b1, w2, b2, w3, b3, Qm, Km, Vm);
    attn_kernel<<<NB * 128, 256, 0, stream>>>(Qm, Km, Vm, gamma, out);
}

// Round 8
// 143.424 us; speedup vs baseline: 1.3293x; 1.1644x over previous
//
#include <hip/hip_runtime.h>
#include <cmath>

#define NB 8
#define CC 256
#define NPIX 4096
#define QB 64
#define KVB 64
#define NT (NPIX / KVB)
#define LOG2E 1.4426950408889634f

typedef __attribute__((ext_vector_type(4))) float f32x4;
typedef __attribute__((ext_vector_type(8))) short s16x8;
typedef __attribute__((ext_vector_type(4))) unsigned short u16x4;
typedef __attribute__((ext_vector_type(4))) unsigned int u32x4;
typedef __attribute__((ext_vector_type(2))) unsigned int u32x2;

__device__ __forceinline__ unsigned short f2bf(float f) {
    union { float f; unsigned int u; } v; v.f = f;
    return (unsigned short)((v.u + 0x7FFFu + ((v.u >> 16) & 1u)) >> 16);
}

__device__ __forceinline__ unsigned int cvt_pk_bf16(float lo, float hi) {
    unsigned int r;
    asm("v_cvt_pk_bf16_f32 %0, %1, %2" : "=v"(r) : "v"(lo), "v"(hi));
    return r;  // low16 = bf16(lo), high16 = bf16(hi), RNE
}

__device__ __forceinline__ float u2f(unsigned int u) {
    union { unsigned int u; float f; } v; v.u = u; return v.f;
}

// ---------------------------------------------------------------------------
// proj_gemm: [Q(32);K(32);V(256)] = W · x  via MFMA, 2-term x hi/lo split.
// (unchanged — passed, ~14 µs)
// ---------------------------------------------------------------------------
__global__ __launch_bounds__(320) void proj_gemm_kernel(
    const float* __restrict__ x,
    const float* __restrict__ w1, const float* __restrict__ b1,
    const float* __restrict__ w2, const float* __restrict__ b2,
    const float* __restrict__ w3, const float* __restrict__ b3,
    unsigned short* __restrict__ Qm, unsigned short* __restrict__ Km,
    unsigned short* __restrict__ Vm)
{
    const int b  = blockIdx.x >> 6;
    const int n0 = (blockIdx.x & 63) * 64;
    const int wave = threadIdx.x >> 6;
    const int lane = threadIdx.x & 63;
    const int cl = lane & 15, g = lane >> 4;

    const float* arow[4];
#pragma unroll
    for (int ct = 0; ct < 4; ++ct) {
        const int row = wave * 64 + ct * 16 + cl;  // 0..319
        if (row < 32)       arow[ct] = w1 + (size_t)row * 256;
        else if (row < 64)  arow[ct] = w2 + (size_t)(row - 32) * 256;
        else                arow[ct] = w3 + (size_t)(row - 64) * 256;
    }

    const float* xb = x + (size_t)b * CC * NPIX + n0 + cl;

    f32x4 acc[4][4];
#pragma unroll
    for (int ct = 0; ct < 4; ++ct)
#pragma unroll
        for (int nt = 0; nt < 4; ++nt) acc[ct][nt] = (f32x4){0.f, 0.f, 0.f, 0.f};

    for (int ks = 0; ks < 8; ++ks) {
        const int c0 = ks * 32;
        s16x8 ah[4];
#pragma unroll
        for (int ct = 0; ct < 4; ++ct) {
            const float* ap = arow[ct] + c0 + g * 8;
            f32x4 a0 = *(const f32x4*)ap;
            f32x4 a1 = *(const f32x4*)(ap + 4);
            u32x4 u;
            u[0] = cvt_pk_bf16(a0[0], a0[1]); u[1] = cvt_pk_bf16(a0[2], a0[3]);
            u[2] = cvt_pk_bf16(a1[0], a1[1]); u[3] = cvt_pk_bf16(a1[2], a1[3]);
            ah[ct] = __builtin_bit_cast(s16x8, u);
        }
#pragma unroll
        for (int nt = 0; nt < 4; ++nt) {
            const float* xp = xb + (size_t)(c0 + g * 8) * NPIX + nt * 16;
            float xe[8];
#pragma unroll
            for (int e = 0; e < 8; ++e) xe[e] = xp[(size_t)e * NPIX];
            u32x4 uh, ul;
#pragma unroll
            for (int p = 0; p < 4; ++p) {
                const unsigned int hp = cvt_pk_bf16(xe[2 * p], xe[2 * p + 1]);
                const float h0 = u2f(hp << 16);
                const float h1 = u2f(hp & 0xffff0000u);
                uh[p] = hp;
                ul[p] = cvt_pk_bf16(xe[2 * p] - h0, xe[2 * p + 1] - h1);
            }
            const s16x8 bh = __builtin_bit_cast(s16x8, uh);
            const s16x8 bl = __builtin_bit_cast(s16x8, ul);
#pragma unroll
            for (int ct = 0; ct < 4; ++ct)
                acc[ct][nt] = __builtin_amdgcn_mfma_f32_16x16x32_bf16(ah[ct], bh, acc[ct][nt], 0, 0, 0);
#pragma unroll
            for (int ct = 0; ct < 4; ++ct)
                acc[ct][nt] = __builtin_amdgcn_mfma_f32_16x16x32_bf16(ah[ct], bl, acc[ct][nt], 0, 0, 0);
        }
    }

    if (wave == 0) {
#pragma unroll
        for (int ct = 0; ct < 4; ++ct) {
#pragma unroll
            for (int nt = 0; nt < 4; ++nt) {
                const int n = n0 + nt * 16 + cl;
                const int co = ct * 16 + g * 4;
                f32x4 v = acc[ct][nt];
                if (ct < 2) {  // Q, pre-scaled by log2e
                    const float q0 = (v[0] + b1[co + 0]) * LOG2E;
                    const float q1 = (v[1] + b1[co + 1]) * LOG2E;
                    const float q2 = (v[2] + b1[co + 2]) * LOG2E;
                    const float q3 = (v[3] + b1[co + 3]) * LOG2E;
                    u32x2 dd = {cvt_pk_bf16(q0, q1), cvt_pk_bf16(q2, q3)};
                    *(u32x2*)(Qm + ((size_t)b * NPIX + n) * 32 + co) = dd;
                } else {
                    const int ko = co - 32;
                    const float k0 = v[0] + b2[ko + 0];
                    const float k1 = v[1] + b2[ko + 1];
                    const float k2 = v[2] + b2[ko + 2];
                    const float k3 = v[3] + b2[ko + 3];
                    u32x2 dd = {cvt_pk_bf16(k0, k1), cvt_pk_bf16(k2, k3)};
                    *(u32x2*)(Km + ((size_t)b * NPIX + n) * 32 + ko) = dd;
                }
            }
        }
    } else {
        const int cvb = (wave - 1) * 64;
#pragma unroll
        for (int ct = 0; ct < 4; ++ct) {
#pragma unroll
            for (int nt = 0; nt < 4; ++nt) {
                const int n = n0 + nt * 16 + cl;
                const int cv = cvb + ct * 16 + g * 4;
#pragma unroll
                for (int r = 0; r < 4; ++r)
                    Vm[((size_t)b * CC + cv + r) * NPIX + n] = f2bf(acc[ct][nt][r] + b3[cv + r]);
            }
        }
    }
}

// ---------------------------------------------------------------------------
// attn v7: 512-thread blocks (8 waves), grid 512 -> 2 blocks/CU = 16 waves/CU
// with ZERO redundant work. Every wave owns a 32-channel PV slice; waves 0-3
// additionally own softmax for q-slice [w*16,w*16+16) (once per block, as in
// R4). Two-barrier skeleton, V staged in LDS with reg-prefetch one tile ahead
// (R4 pattern), K prefetched via R6's proven kf/kf2 rotate (issued after
// P-write to cap VGPR). LDS 41KB, VGPR<=128 (launch_bounds 512,4).
// ---------------------------------------------------------------------------
__global__ __launch_bounds__(512, 4) void attn_kernel(
    const unsigned short* __restrict__ Qm, const unsigned short* __restrict__ Km,
    const unsigned short* __restrict__ Vm, const float* __restrict__ gamma,
    float* __restrict__ out)
{
    __shared__ unsigned short Vs[CC * KVB];  // [c][m] 32KB, 16B-slot XOR swizzle
    __shared__ unsigned short Ps[QB * KVB];  // [q][m]  8KB, swizzled
    __shared__ float alpha_lds[QB];          // per-q rescale factor
    __shared__ float l_lds[QB];              // final denominators

    // XCD swizzle: each XCD gets one batch's 64 q-blocks (K+V fit its 4MB L2)
    const int bid = ((blockIdx.x & 7) << 6) + (blockIdx.x >> 3);
    const int b = bid >> 6;
    const int q0 = (bid & 63) * QB;

    const int t = threadIdx.x;
    const int wave = t >> 6;
    const int lane = t & 63;
    const int cl = lane & 15;
    const int g = lane >> 4;
    const int c0w = wave * 32;                 // this wave's channel slice
    const bool owner = wave < 4;               // softmax owner waves
    const int qrow_own = (wave & 3) * 16 + cl; // owned q-row (waves 0-3)

    // Q B-frag for the owned q-slice: B[k=d][col=q]
    const s16x8 qf = *(const s16x8*)(Qm + (((size_t)b * NPIX) + q0 + qrow_own) * 32 + g * 8);

    f32x4 acc[4][2];  // [qt][ct]: q = qt*16+cl, c = c0w + ct*16 + g*4 + r
#pragma unroll
    for (int qt = 0; qt < 4; ++qt)
#pragma unroll
        for (int ct = 0; ct < 2; ++ct)
            acc[qt][ct] = (f32x4){0.f, 0.f, 0.f, 0.f};

    float mrun = -__builtin_inff();
    float lrun = 0.f;  // per-lane partial; g-reduced once in epilogue

    const unsigned short* Kg = Km + (size_t)b * NPIX * 32;
    const unsigned short* Vg = Vm + (size_t)b * CC * NPIX;

    // V staging: 512 threads, 8 chunks/row -> 64 rows/pass, 4 passes
    const int vin = t & 7;
    const int vr0 = t >> 3;  // 0..63; (vr0 + i*64)&7 == vr0&7
    const unsigned short* vsrc = Vg + (size_t)vr0 * NPIX + vin * 8;
    unsigned short* vdst = &Vs[vr0 * 64 + ((vin ^ (vr0 & 7)) << 3)];

    // prologue: prefetch V tile 0 into regs; K frags for tile 0
    s16x8 vreg[4];
#pragma unroll
    for (int i = 0; i < 4; ++i)
        vreg[i] = *(const s16x8*)(vsrc + (size_t)i * 64 * NPIX);

    s16x8 kf[4];
#pragma unroll
    for (int mt = 0; mt < 4; ++mt)
        kf[mt] = *(const s16x8*)(Kg + (size_t)(mt * 16 + cl) * 32 + g * 8);

    for (int it = 0; it < NT; ++it) {
        __syncthreads();  // barrier1: prev iter's Vs/Ps/alpha reads complete

        // commit prefetched V tile to LDS
#pragma unroll
        for (int i = 0; i < 4; ++i)
            *(s16x8*)(vdst + i * 64 * 64) = vreg[i];

        // issue next V tile's loads (wrap on last iter; in flight across
        // softmax + barrier + PV)
        {
            const int mn = ((it + 1) & (NT - 1)) * KVB;
#pragma unroll
            for (int i = 0; i < 4; ++i)
                vreg[i] = *(const s16x8*)(vsrc + (size_t)i * 64 * NPIX + mn);
        }

        if (owner) {
            // QK^T for owned q-slice: S^T tiles D[row=m][col=q]
            f32x4 s[4];
            __builtin_amdgcn_s_setprio(1);
#pragma unroll
            for (int mt = 0; mt < 4; ++mt) {
                f32x4 z = (f32x4){0.f, 0.f, 0.f, 0.f};
                s[mt] = __builtin_amdgcn_mfma_f32_16x16x32_bf16(kf[mt], qf, z, 0, 0, 0);
            }
            __builtin_amdgcn_s_setprio(0);

            // online softmax over m (log2 domain; Q pre-scaled by log2e)
            float ml = -__builtin_inff();
#pragma unroll
            for (int mt = 0; mt < 4; ++mt)
#pragma unroll
                for (int r = 0; r < 4; ++r) ml = fmaxf(ml, s[mt][r]);
            ml = fmaxf(ml, __shfl_xor(ml, 16, 64));
            ml = fmaxf(ml, __shfl_xor(ml, 32, 64));

            float alpha = 1.f;
            if (!__all(ml <= mrun + 8.f)) {  // defer-max (T13)
                const float mnew = fmaxf(mrun, ml);
                alpha = __builtin_amdgcn_exp2f(mrun - mnew);
                mrun = mnew;
                lrun *= alpha;
            }
            if (g == 0) alpha_lds[qrow_own] = alpha;

#pragma unroll
            for (int mt = 0; mt < 4; ++mt) {
#pragma unroll
                for (int r = 0; r < 4; ++r) {
                    s[mt][r] = __builtin_amdgcn_exp2f(s[mt][r] - mrun);
                    lrun += s[mt][r];  // per-lane partial (uniform alpha)
                }
            }

            // pack P slice -> Ps [q][m], swizzled (8B writes via cvt_pk)
#pragma unroll
            for (int mt = 0; mt < 4; ++mt) {
                u32x2 dd = {cvt_pk_bf16(s[mt][0], s[mt][1]),
                            cvt_pk_bf16(s[mt][2], s[mt][3])};
                *(u32x2*)(&Ps[qrow_own * 64 + ((mt * 16 + g * 4) ^ ((qrow_own & 7) << 3))]) = dd;
            }

            // prefetch next K frags (wrap; issued late to cap live VGPRs)
            const int mnext = ((it + 1) & (NT - 1)) * KVB;
#pragma unroll
            for (int mt = 0; mt < 4; ++mt)
                kf[mt] = *(const s16x8*)(Kg + (size_t)(mnext + mt * 16 + cl) * 32 + g * 8);
        }

        __syncthreads();  // barrier2: Vs + Ps + alpha visible

        // rescale acc by per-q alpha (rare thanks to defer-max)
        float aq[4];
#pragma unroll
        for (int qt = 0; qt < 4; ++qt) aq[qt] = alpha_lds[qt * 16 + cl];
        if (__any(aq[0] != 1.f || aq[1] != 1.f || aq[2] != 1.f || aq[3] != 1.f)) {
#pragma unroll
            for (int qt = 0; qt < 4; ++qt)
#pragma unroll
                for (int ct = 0; ct < 2; ++ct) acc[qt][ct] *= aq[qt];
        }

        // PV: acc[qt][ct] += mfma(A=V[c][m] (LDS), B=P^T[m][q] (LDS))
#pragma unroll
        for (int ch = 0; ch < 2; ++ch) {
            s16x8 pb[4];
#pragma unroll
            for (int qt = 0; qt < 4; ++qt) {
                const int qr = qt * 16 + cl;
                pb[qt] = *(const s16x8*)(&Ps[qr * 64 + ((ch * 32 + g * 8) ^ ((qr & 7) << 3))]);
            }
            __builtin_amdgcn_s_setprio(1);
#pragma unroll
            for (int ct = 0; ct < 2; ++ct) {
                const int cr = c0w + ct * 16 + cl;
                s16x8 av = *(const s16x8*)(&Vs[cr * 64 + ((ch * 32 + g * 8) ^ ((cr & 7) << 3))]);
#pragma unroll
                for (int qt = 0; qt < 4; ++qt)
                    acc[qt][ct] = __builtin_amdgcn_mfma_f32_16x16x32_bf16(av, pb[qt], acc[qt][ct], 0, 0, 0);
            }
            __builtin_amdgcn_s_setprio(0);
        }
    }

    // epilogue: owners reduce lrun over g-groups, share denominators
    if (owner) {
        lrun += __shfl_xor(lrun, 16, 64);
        lrun += __shfl_xor(lrun, 32, 64);
        if (g == 0) l_lds[qrow_own] = lrun;
    }
    __syncthreads();

    // coalesced [b][c][n] stores; second output = gamma*val
    const float gm = gamma[0];
    float* out2 = out + (size_t)NB * CC * NPIX;
#pragma unroll
    for (int qt = 0; qt < 4; ++qt) {
        const float inv = 1.f / l_lds[qt * 16 + cl];
        const int n = q0 + qt * 16 + cl;
#pragma unroll
        for (int ct = 0; ct < 2; ++ct) {
#pragma unroll
            for (int r = 0; r < 4; ++r) {
                const int chn = c0w + ct * 16 + g * 4 + r;
                const float val = acc[qt][ct][r] * inv;
                const size_t idx = ((size_t)b * CC + chn) * NPIX + n;
                out[idx] = val;
                out2[idx] = gm * val;
            }
        }
    }
}

// ---------------------------------------------------------------------------
extern "C" void kernel_launch(void* const* d_in, const int* in_sizes, int n_in,
                              void* d_out, int out_size, void* d_ws, size_t ws_size,
                              hipStream_t stream) {
    (void)in_sizes; (void)n_in; (void)out_size; (void)ws_size;
    const float* x     = (const float*)d_in[0];
    const float* w1    = (const float*)d_in[1];
    const float* b1    = (const float*)d_in[2];
    const float* w2    = (const float*)d_in[3];
    const float* b2    = (const float*)d_in[4];
    const float* w3    = (const float*)d_in[5];
    const float* b3    = (const float*)d_in[6];
    const float* gamma = (const float*)d_in[7];
    float* out = (float*)d_out;

    unsigned short* Qm = (unsigned short*)d_ws;                       // 2 MB
    unsigned short* Km = Qm + (size_t)NB * NPIX * 32;                 // 2 MB
    unsigned short* Vm = Km + (size_t)NB * NPIX * 32;                 // 16 MB

    proj_gemm_kernel<<<NB * 64, 320, 0, stream>>>(x, w1, b1, w2, b2, w3, b3, Qm, Km, Vm);
    attn_kernel<<<NB * 64, 512, 0, stream>>>(Qm, Km, Vm, gamma, out);
}